// Round 1
// baseline (778.877 us; speedup 1.0000x reference)
//
#include <hip/hip_runtime.h>
#include <hip/hip_bf16.h>
#include <math.h>

#define B_ 8
#define L_ 2048
#define D_ 1024
#define CTX_ELEMS (B_ * L_ * D_)   /* 16,777,216 */
#define ATT_ELEMS (B_ * L_ * L_)   /* 33,554,432 */

typedef __bf16 bf16x8 __attribute__((ext_vector_type(8)));
typedef float f32x4 __attribute__((ext_vector_type(4)));
typedef unsigned short u16x8 __attribute__((ext_vector_type(8)));

// LDS tile: 128 rows x 32 k, padded to stride 40 (breaks the 8-way bank
// conflict a 64B row stride would give on ds_read_b128 fragments).
#define LDK 40

__device__ __forceinline__ unsigned short f2bf(float f) {
    union { float f; unsigned u; } c; c.f = f;
    unsigned u = c.u;
    u += 0x7fffu + ((u >> 16) & 1u);   // RNE
    return (unsigned short)(u >> 16);
}

// ---------------------------------------------------------------------------
// Kernel 1: projections.  out[m][n] = sum_d A[m][d] * W[n][d]   (y = x @ W^T)
// z=0: k = x@Wk^T ; z=1: v = x@Wv^T ; z=2: q = y@Wq^T.  Output bf16 (ushort).
// ---------------------------------------------------------------------------
__global__ __launch_bounds__(256) void proj_kernel(
    const float* __restrict__ x, const float* __restrict__ y,
    const float* __restrict__ Wk, const float* __restrict__ Wv,
    const float* __restrict__ Wq,
    unsigned short* __restrict__ kb, unsigned short* __restrict__ vb,
    unsigned short* __restrict__ qb)
{
    const float* A; const float* W; unsigned short* out;
    if (blockIdx.z == 0)      { A = x; W = Wk; out = kb; }
    else if (blockIdx.z == 1) { A = x; W = Wv; out = vb; }
    else                      { A = y; W = Wq; out = qb; }

    __shared__ unsigned short sA[128 * LDK];
    __shared__ unsigned short sB[128 * LDK];

    const int tid  = threadIdx.x;
    const int m0   = blockIdx.x * 128;
    const int n0   = blockIdx.y * 128;
    const int row  = tid >> 1;
    const int half = tid & 1;

    const int wave = tid >> 6, lane = tid & 63;
    const int wr = wave >> 1, wc = wave & 1;
    const int lrow = lane & 15, quad = lane >> 4;

    f32x4 acc[4][4];
#pragma unroll
    for (int i = 0; i < 4; i++)
#pragma unroll
        for (int j = 0; j < 4; j++) acc[i][j] = (f32x4){0.f, 0.f, 0.f, 0.f};

    for (int k0 = 0; k0 < D_; k0 += 32) {
        // ---- stage A (fp32 -> bf16) ----
        {
            const float* src = A + (size_t)(m0 + row) * D_ + k0 + half * 16;
            float4 f0 = ((const float4*)src)[0];
            float4 f1 = ((const float4*)src)[1];
            float4 f2 = ((const float4*)src)[2];
            float4 f3 = ((const float4*)src)[3];
            u16x8 p0 = { f2bf(f0.x), f2bf(f0.y), f2bf(f0.z), f2bf(f0.w),
                         f2bf(f1.x), f2bf(f1.y), f2bf(f1.z), f2bf(f1.w) };
            u16x8 p1 = { f2bf(f2.x), f2bf(f2.y), f2bf(f2.z), f2bf(f2.w),
                         f2bf(f3.x), f2bf(f3.y), f2bf(f3.z), f2bf(f3.w) };
            unsigned short* dst = &sA[row * LDK + half * 16];
            *(u16x8*)dst = p0;
            *(u16x8*)(dst + 8) = p1;
        }
        // ---- stage B = W rows (fp32 -> bf16) ----
        {
            const float* src = W + (size_t)(n0 + row) * D_ + k0 + half * 16;
            float4 f0 = ((const float4*)src)[0];
            float4 f1 = ((const float4*)src)[1];
            float4 f2 = ((const float4*)src)[2];
            float4 f3 = ((const float4*)src)[3];
            u16x8 p0 = { f2bf(f0.x), f2bf(f0.y), f2bf(f0.z), f2bf(f0.w),
                         f2bf(f1.x), f2bf(f1.y), f2bf(f1.z), f2bf(f1.w) };
            u16x8 p1 = { f2bf(f2.x), f2bf(f2.y), f2bf(f2.z), f2bf(f2.w),
                         f2bf(f3.x), f2bf(f3.y), f2bf(f3.z), f2bf(f3.w) };
            unsigned short* dst = &sB[row * LDK + half * 16];
            *(u16x8*)dst = p0;
            *(u16x8*)(dst + 8) = p1;
        }
        __syncthreads();

        bf16x8 av[4], bv[4];
#pragma unroll
        for (int i = 0; i < 4; i++)
            av[i] = *(const bf16x8*)&sA[(wr * 64 + i * 16 + lrow) * LDK + quad * 8];
#pragma unroll
        for (int j = 0; j < 4; j++)
            bv[j] = *(const bf16x8*)&sB[(wc * 64 + j * 16 + lrow) * LDK + quad * 8];
#pragma unroll
        for (int i = 0; i < 4; i++)
#pragma unroll
            for (int j = 0; j < 4; j++)
                acc[i][j] = __builtin_amdgcn_mfma_f32_16x16x32_bf16(
                    av[i], bv[j], acc[i][j], 0, 0, 0);
        __syncthreads();
    }

    // epilogue: fp32 acc -> bf16 store
#pragma unroll
    for (int i = 0; i < 4; i++) {
        const int m = m0 + wr * 64 + i * 16 + quad * 4;
#pragma unroll
        for (int j = 0; j < 4; j++) {
            const int n = n0 + wc * 64 + j * 16 + lrow;
#pragma unroll
            for (int r = 0; r < 4; r++)
                out[(size_t)(m + r) * D_ + n] = f2bf(acc[i][j][r]);
        }
    }
}

// ---------------------------------------------------------------------------
// Kernel 2: scores[b][m][n] = (1/32) * sum_d q[b][m][d] * k[b][n][d]  (fp32 out)
// ---------------------------------------------------------------------------
__global__ __launch_bounds__(256) void scores_kernel(
    const unsigned short* __restrict__ qb, const unsigned short* __restrict__ kb,
    float* __restrict__ attn)
{
    const int bz = blockIdx.z;
    const unsigned short* Aq = qb + (size_t)bz * L_ * D_;
    const unsigned short* Bk = kb + (size_t)bz * L_ * D_;
    float* out = attn + (size_t)bz * L_ * L_;

    __shared__ unsigned short sA[128 * LDK];
    __shared__ unsigned short sB[128 * LDK];

    const int tid  = threadIdx.x;
    const int m0   = blockIdx.x * 128;
    const int n0   = blockIdx.y * 128;
    const int row  = tid >> 1;
    const int half = tid & 1;

    const int wave = tid >> 6, lane = tid & 63;
    const int wr = wave >> 1, wc = wave & 1;
    const int lrow = lane & 15, quad = lane >> 4;

    f32x4 acc[4][4];
#pragma unroll
    for (int i = 0; i < 4; i++)
#pragma unroll
        for (int j = 0; j < 4; j++) acc[i][j] = (f32x4){0.f, 0.f, 0.f, 0.f};

    for (int k0 = 0; k0 < D_; k0 += 32) {
        {
            const unsigned short* src = Aq + (size_t)(m0 + row) * D_ + k0 + half * 16;
            u16x8 v0 = ((const u16x8*)src)[0];
            u16x8 v1 = ((const u16x8*)src)[1];
            unsigned short* dst = &sA[row * LDK + half * 16];
            *(u16x8*)dst = v0; *(u16x8*)(dst + 8) = v1;
        }
        {
            const unsigned short* src = Bk + (size_t)(m0 * 0 + n0 + row) * D_ + k0 + half * 16;
            u16x8 v0 = ((const u16x8*)src)[0];
            u16x8 v1 = ((const u16x8*)src)[1];
            unsigned short* dst = &sB[row * LDK + half * 16];
            *(u16x8*)dst = v0; *(u16x8*)(dst + 8) = v1;
        }
        __syncthreads();

        bf16x8 av[4], bv[4];
#pragma unroll
        for (int i = 0; i < 4; i++)
            av[i] = *(const bf16x8*)&sA[(wr * 64 + i * 16 + lrow) * LDK + quad * 8];
#pragma unroll
        for (int j = 0; j < 4; j++)
            bv[j] = *(const bf16x8*)&sB[(wc * 64 + j * 16 + lrow) * LDK + quad * 8];
#pragma unroll
        for (int i = 0; i < 4; i++)
#pragma unroll
            for (int j = 0; j < 4; j++)
                acc[i][j] = __builtin_amdgcn_mfma_f32_16x16x32_bf16(
                    av[i], bv[j], acc[i][j], 0, 0, 0);
        __syncthreads();
    }

#pragma unroll
    for (int i = 0; i < 4; i++) {
        const int m = m0 + wr * 64 + i * 16 + quad * 4;
#pragma unroll
        for (int j = 0; j < 4; j++) {
            const int n = n0 + wc * 64 + j * 16 + lrow;
#pragma unroll
            for (int r = 0; r < 4; r++)
                out[(size_t)(m + r) * L_ + n] = acc[i][j][r] * 0.03125f;
        }
    }
}

// ---------------------------------------------------------------------------
// Kernel 3: row softmax, in place.  Masked query rows -> exactly 1/2048.
// ---------------------------------------------------------------------------
__global__ __launch_bounds__(256) void softmax_kernel(
    float* __restrict__ attn, const int* __restrict__ lens)
{
    const int r  = blockIdx.x;        // 0..16383
    const int b  = r >> 11;
    const int qi = r & 2047;
    float* rowp = attn + (size_t)r * L_;
    const int tid = threadIdx.x;

    if (qi >= lens[b]) {
        const float u = 1.0f / 2048.0f;
#pragma unroll
        for (int j = 0; j < 8; j++) rowp[j * 256 + tid] = u;
        return;
    }

    float v[8];
#pragma unroll
    for (int j = 0; j < 8; j++) v[j] = rowp[j * 256 + tid];

    float m = v[0];
#pragma unroll
    for (int j = 1; j < 8; j++) m = fmaxf(m, v[j]);
#pragma unroll
    for (int off = 32; off > 0; off >>= 1) m = fmaxf(m, __shfl_xor(m, off, 64));

    __shared__ float redm[4];
    __shared__ float reds[4];
    const int wave = tid >> 6, lane = tid & 63;
    if (lane == 0) redm[wave] = m;
    __syncthreads();
    m = fmaxf(fmaxf(redm[0], redm[1]), fmaxf(redm[2], redm[3]));

    float s = 0.f;
#pragma unroll
    for (int j = 0; j < 8; j++) { v[j] = __expf(v[j] - m); s += v[j]; }
#pragma unroll
    for (int off = 32; off > 0; off >>= 1) s += __shfl_xor(s, off, 64);
    if (lane == 0) reds[wave] = s;
    __syncthreads();
    s = reds[0] + reds[1] + reds[2] + reds[3];

    const float inv = 1.0f / s;
#pragma unroll
    for (int j = 0; j < 8; j++) rowp[j * 256 + tid] = v[j] * inv;
}

// ---------------------------------------------------------------------------
// Kernel 4: context[b][m][n] = sum_k attn[b][m][k] * v[b][k][n]   (NN GEMM)
// A = attn fp32 (converted in staging), B = v bf16 staged TRANSPOSED so
// B-fragments are contiguous ds_read_b128: sB[n][k] = v[k0+k][n0+n].
// ---------------------------------------------------------------------------
__global__ __launch_bounds__(256) void context_kernel(
    const float* __restrict__ attn, const unsigned short* __restrict__ vb,
    float* __restrict__ ctx)
{
    const int bz = blockIdx.z;
    const float* Aa = attn + (size_t)bz * L_ * L_;
    const unsigned short* Bv = vb + (size_t)bz * L_ * D_;
    float* out = ctx + (size_t)bz * L_ * D_;

    __shared__ unsigned short sA[128 * LDK];
    __shared__ unsigned short sB[128 * LDK];

    const int tid  = threadIdx.x;
    const int m0   = blockIdx.x * 128;
    const int n0   = blockIdx.y * 128;
    const int row  = tid >> 1;
    const int half = tid & 1;

    const int wave = tid >> 6, lane = tid & 63;
    const int wr = wave >> 1, wc = wave & 1;
    const int lrow = lane & 15, quad = lane >> 4;

    f32x4 acc[4][4];
#pragma unroll
    for (int i = 0; i < 4; i++)
#pragma unroll
        for (int j = 0; j < 4; j++) acc[i][j] = (f32x4){0.f, 0.f, 0.f, 0.f};

    for (int k0 = 0; k0 < L_; k0 += 32) {
        // ---- stage A tile from fp32 attn ----
        {
            const float* src = Aa + (size_t)(m0 + row) * L_ + k0 + half * 16;
            float4 f0 = ((const float4*)src)[0];
            float4 f1 = ((const float4*)src)[1];
            float4 f2 = ((const float4*)src)[2];
            float4 f3 = ((const float4*)src)[3];
            u16x8 p0 = { f2bf(f0.x), f2bf(f0.y), f2bf(f0.z), f2bf(f0.w),
                         f2bf(f1.x), f2bf(f1.y), f2bf(f1.z), f2bf(f1.w) };
            u16x8 p1 = { f2bf(f2.x), f2bf(f2.y), f2bf(f2.z), f2bf(f2.w),
                         f2bf(f3.x), f2bf(f3.y), f2bf(f3.z), f2bf(f3.w) };
            unsigned short* dst = &sA[row * LDK + half * 16];
            *(u16x8*)dst = p0; *(u16x8*)(dst + 8) = p1;
        }
        // ---- stage B tile transposed: sB[n][k] = v[k0+kk][n0+nc*8+e] ----
#pragma unroll
        for (int c = tid; c < 512; c += 256) {
            const int kk = c & 31;
            const int nc = c >> 5;   // 0..15
            u16x8 vv = *(const u16x8*)(Bv + (size_t)(k0 + kk) * D_ + n0 + nc * 8);
            unsigned short* dst = &sB[(nc * 8) * LDK + kk];
#pragma unroll
            for (int e = 0; e < 8; e++) dst[e * LDK] = vv[e];
        }
        __syncthreads();

        bf16x8 av[4], bv4[4];
#pragma unroll
        for (int i = 0; i < 4; i++)
            av[i] = *(const bf16x8*)&sA[(wr * 64 + i * 16 + lrow) * LDK + quad * 8];
#pragma unroll
        for (int j = 0; j < 4; j++)
            bv4[j] = *(const bf16x8*)&sB[(wc * 64 + j * 16 + lrow) * LDK + quad * 8];
#pragma unroll
        for (int i = 0; i < 4; i++)
#pragma unroll
            for (int j = 0; j < 4; j++)
                acc[i][j] = __builtin_amdgcn_mfma_f32_16x16x32_bf16(
                    av[i], bv4[j], acc[i][j], 0, 0, 0);
        __syncthreads();
    }

#pragma unroll
    for (int i = 0; i < 4; i++) {
        const int m = m0 + wr * 64 + i * 16 + quad * 4;
#pragma unroll
        for (int j = 0; j < 4; j++) {
            const int n = n0 + wc * 64 + j * 16 + lrow;
#pragma unroll
            for (int r = 0; r < 4; r++)
                out[(size_t)(m + r) * D_ + n] = acc[i][j][r];
        }
    }
}

// ---------------------------------------------------------------------------
extern "C" void kernel_launch(void* const* d_in, const int* in_sizes, int n_in,
                              void* d_out, int out_size, void* d_ws, size_t ws_size,
                              hipStream_t stream) {
    const float* x    = (const float*)d_in[0];  // input_seq  [B,L,D]
    const int*   lens = (const int*)d_in[1];    // input_lens [B]
    const float* y    = (const float*)d_in[2];  // output_seq [B,L,D]
    const float* Wk   = (const float*)d_in[3];
    const float* Wv   = (const float*)d_in[4];
    const float* Wq   = (const float*)d_in[5];

    float* ctx  = (float*)d_out;                 // [B,L,D]
    float* attn = (float*)d_out + CTX_ELEMS;     // [B,L,L]

    // workspace: q,k,v in bf16 (ushort), 32 MB each = 96 MB total
    unsigned short* qb = (unsigned short*)d_ws;
    unsigned short* kb = qb + CTX_ELEMS;
    unsigned short* vb = kb + CTX_ELEMS;

    proj_kernel<<<dim3(128, 8, 3), 256, 0, stream>>>(x, y, Wk, Wv, Wq, kb, vb, qb);
    scores_kernel<<<dim3(16, 16, B_), 256, 0, stream>>>(qb, kb, attn);
    softmax_kernel<<<dim3(B_ * L_), 256, 0, stream>>>(attn, lens);
    context_kernel<<<dim3(16, 8, B_), 256, 0, stream>>>(attn, vb, ctx);
}

// Round 2
// 655.618 us; speedup vs baseline: 1.1880x; 1.1880x over previous
//
#include <hip/hip_runtime.h>
#include <hip/hip_bf16.h>

#define B_ 8
#define L_ 2048
#define D_ 1024
#define CTX_ELEMS (B_ * L_ * D_)   /* 16,777,216 */

typedef __bf16 bf16x8 __attribute__((ext_vector_type(8)));
typedef float f32x4 __attribute__((ext_vector_type(4)));
typedef unsigned short u16x8 __attribute__((ext_vector_type(8)));
typedef unsigned short u16x4 __attribute__((ext_vector_type(4)));

typedef __attribute__((address_space(1))) void GV;
typedef __attribute__((address_space(3))) void LV;
// async global->LDS, 16B per lane; LDS dst = wave-uniform base + lane*16
#define GLL16(g, l) __builtin_amdgcn_global_load_lds((GV*)(g), (LV*)(l), 16, 0, 0)

__device__ __forceinline__ unsigned short f2bf(float f) {
    union { float f; unsigned u; } c; c.f = f;
    unsigned u = c.u;
    u += 0x7fffu + ((u >> 16) & 1u);   // RNE
    return (unsigned short)(u >> 16);
}

// ---------------------------------------------------------------------------
// fp32 -> bf16 bulk convert.  blockIdx.y selects tensor.
// ---------------------------------------------------------------------------
__global__ __launch_bounds__(256) void cvt_kernel(
    const float* __restrict__ x, const float* __restrict__ y,
    const float* __restrict__ Wk, const float* __restrict__ Wv,
    const float* __restrict__ Wq,
    unsigned short* __restrict__ xb, unsigned short* __restrict__ yb,
    unsigned short* __restrict__ wkb, unsigned short* __restrict__ wvb,
    unsigned short* __restrict__ wqb)
{
    const float* src; unsigned short* dst; int n4;
    switch (blockIdx.y) {
        case 0:  src = x;  dst = xb;  n4 = CTX_ELEMS / 4; break;
        case 1:  src = y;  dst = yb;  n4 = CTX_ELEMS / 4; break;
        case 2:  src = Wk; dst = wkb; n4 = D_ * D_ / 4;   break;
        case 3:  src = Wv; dst = wvb; n4 = D_ * D_ / 4;   break;
        default: src = Wq; dst = wqb; n4 = D_ * D_ / 4;   break;
    }
    const int stride = gridDim.x * 256;
    for (int i = blockIdx.x * 256 + threadIdx.x; i < n4; i += stride) {
        float4 f = ((const float4*)src)[i];
        u16x4 o = { f2bf(f.x), f2bf(f.y), f2bf(f.z), f2bf(f.w) };
        ((u16x4*)dst)[i] = o;
    }
}

// ---------------------------------------------------------------------------
// m97-style NT GEMM core: out[m][n] = sum_k A[m][k]*B[n][k], 128x128x32 tiles,
// unpadded [128][32] bf16 LDS tiles filled by global_load_lds dwordx4.
// ---------------------------------------------------------------------------
#define GEMM_VARS                                              \
    const int tid = threadIdx.x;                               \
    const int wave = tid >> 6, lane = tid & 63;                \
    const int wr = wave >> 1, wc = wave & 1;                   \
    const int lrow = lane & 15, quad = lane >> 4;              \
    const int gr = lane >> 2, gc = (lane & 3) * 8;

#define GEMM_KLOOP(Ag, lda, Bg, ldb, K)                                        \
    for (int k0 = 0; k0 < (K); k0 += 32) {                                     \
        __syncthreads();                                                       \
        _Pragma("unroll")                                                      \
        for (int r = 0; r < 2; r++) {                                          \
            const int seg = wave * 2 + r;                                      \
            GLL16((Ag) + (size_t)(m0 + seg * 16 + gr) * (lda) + k0 + gc,       \
                  sA + seg * 512);                                             \
            GLL16((Bg) + (size_t)(n0 + seg * 16 + gr) * (ldb) + k0 + gc,       \
                  sB + seg * 512);                                             \
        }                                                                      \
        __syncthreads();                                                       \
        bf16x8 av[4], bv[4];                                                   \
        _Pragma("unroll")                                                      \
        for (int i = 0; i < 4; i++)                                            \
            av[i] = *(const bf16x8*)&sA[(wr * 64 + i * 16 + lrow) * 32 + quad * 8]; \
        _Pragma("unroll")                                                      \
        for (int j = 0; j < 4; j++)                                            \
            bv[j] = *(const bf16x8*)&sB[(wc * 64 + j * 16 + lrow) * 32 + quad * 8]; \
        _Pragma("unroll")                                                      \
        for (int i = 0; i < 4; i++)                                            \
            _Pragma("unroll")                                                  \
            for (int j = 0; j < 4; j++)                                        \
                acc[i][j] = __builtin_amdgcn_mfma_f32_16x16x32_bf16(           \
                    av[i], bv[j], acc[i][j], 0, 0, 0);                         \
    }

// ---------------------------------------------------------------------------
// Projections: z=0 k=x@Wk^T -> kb[l][d]; z=1 v=x@Wv^T -> vtb[d][l] (transposed
// via LDS epilogue); z=2 q=y@Wq^T -> qb[l][d].  All bf16 in/out.
// ---------------------------------------------------------------------------
__global__ __launch_bounds__(256) void proj_kernel(
    const unsigned short* __restrict__ xb, const unsigned short* __restrict__ yb,
    const unsigned short* __restrict__ wkb, const unsigned short* __restrict__ wvb,
    const unsigned short* __restrict__ wqb,
    unsigned short* __restrict__ kb, unsigned short* __restrict__ qb,
    unsigned short* __restrict__ vtb)
{
    __shared__ unsigned short smem[128 * 136];  // staging uses 8192; epi transpose 128x136
    unsigned short* sA = smem;
    unsigned short* sB = smem + 4096;

    const unsigned short* Ag; const unsigned short* Bg;
    const int z = blockIdx.z;
    if (z == 0)      { Ag = xb; Bg = wkb; }
    else if (z == 1) { Ag = xb; Bg = wvb; }
    else             { Ag = yb; Bg = wqb; }

    const int m0 = blockIdx.x * 128;
    const int n0 = blockIdx.y * 128;
    GEMM_VARS

    f32x4 acc[4][4];
#pragma unroll
    for (int i = 0; i < 4; i++)
#pragma unroll
        for (int j = 0; j < 4; j++) acc[i][j] = (f32x4){0.f, 0.f, 0.f, 0.f};

    GEMM_KLOOP(Ag, D_, Bg, D_, D_)

    if (z != 1) {
        unsigned short* out = (z == 0) ? kb : qb;
#pragma unroll
        for (int i = 0; i < 4; i++) {
            const int m = m0 + wr * 64 + i * 16 + quad * 4;
#pragma unroll
            for (int j = 0; j < 4; j++) {
                const int n = n0 + wc * 64 + j * 16 + lrow;
#pragma unroll
                for (int r = 0; r < 4; r++)
                    out[(size_t)(m + r) * D_ + n] = f2bf(acc[i][j][r]);
            }
        }
    } else {
        // transpose through LDS: smem[n][m] (pad 136), then coalesced rows out
        __syncthreads();
#pragma unroll
        for (int i = 0; i < 4; i++) {
            const int m = wr * 64 + i * 16 + quad * 4;
#pragma unroll
            for (int j = 0; j < 4; j++) {
                const int n = wc * 64 + j * 16 + lrow;
#pragma unroll
                for (int r = 0; r < 4; r++)
                    smem[n * 136 + m + r] = f2bf(acc[i][j][r]);
            }
        }
        __syncthreads();
        const int b  = m0 >> 11;
        const int l0 = m0 & 2047;
        unsigned short* vt = vtb + (size_t)b * D_ * L_ + l0;
#pragma unroll
        for (int it = 0; it < 8; it++) {
            const int idx = it * 256 + tid;
            const int n  = idx >> 4;
            const int c8 = (idx & 15) * 8;
            u16x8 val = *(const u16x8*)&smem[n * 136 + c8];
            *(u16x8*)&vt[(size_t)(n0 + n) * L_ + c8] = val;
        }
    }
}

// ---------------------------------------------------------------------------
// scores[b][m][n] = (1/32) sum_d q[m][d] k[n][d]  -> fp32 attn
// ---------------------------------------------------------------------------
__global__ __launch_bounds__(256) void scores_kernel(
    const unsigned short* __restrict__ qb, const unsigned short* __restrict__ kb,
    float* __restrict__ attn)
{
    __shared__ unsigned short sA[4096];
    __shared__ unsigned short sB[4096];
    const int bz = blockIdx.z;
    const unsigned short* Ag = qb + (size_t)bz * L_ * D_;
    const unsigned short* Bg = kb + (size_t)bz * L_ * D_;
    float* out = attn + (size_t)bz * L_ * L_;

    const int m0 = blockIdx.x * 128;
    const int n0 = blockIdx.y * 128;
    GEMM_VARS

    f32x4 acc[4][4];
#pragma unroll
    for (int i = 0; i < 4; i++)
#pragma unroll
        for (int j = 0; j < 4; j++) acc[i][j] = (f32x4){0.f, 0.f, 0.f, 0.f};

    GEMM_KLOOP(Ag, D_, Bg, D_, D_)

#pragma unroll
    for (int i = 0; i < 4; i++) {
        const int m = m0 + wr * 64 + i * 16 + quad * 4;
#pragma unroll
        for (int j = 0; j < 4; j++) {
            const int n = n0 + wc * 64 + j * 16 + lrow;
#pragma unroll
            for (int r = 0; r < 4; r++)
                out[(size_t)(m + r) * L_ + n] = acc[i][j][r] * 0.03125f;
        }
    }
}

// ---------------------------------------------------------------------------
// row softmax in place + bf16 copy.  Masked query rows -> exactly 1/2048.
// ---------------------------------------------------------------------------
__global__ __launch_bounds__(256) void softmax_kernel(
    float* __restrict__ attn, const int* __restrict__ lens,
    unsigned short* __restrict__ attn_bf)
{
    const int r  = blockIdx.x;
    const int b  = r >> 11;
    const int qi = r & 2047;
    float* rowp = attn + (size_t)r * L_;
    unsigned short* rowb = attn_bf + (size_t)r * L_;
    const int tid = threadIdx.x;

    if (qi >= lens[b]) {
        const float u = 1.0f / 2048.0f;
        const unsigned short ub = f2bf(u);
#pragma unroll
        for (int j = 0; j < 8; j++) {
            rowp[j * 256 + tid] = u;
            rowb[j * 256 + tid] = ub;
        }
        return;
    }

    float v[8];
#pragma unroll
    for (int j = 0; j < 8; j++) v[j] = rowp[j * 256 + tid];

    float m = v[0];
#pragma unroll
    for (int j = 1; j < 8; j++) m = fmaxf(m, v[j]);
#pragma unroll
    for (int off = 32; off > 0; off >>= 1) m = fmaxf(m, __shfl_xor(m, off, 64));

    __shared__ float redm[4];
    __shared__ float reds[4];
    const int wave = tid >> 6, lane = tid & 63;
    if (lane == 0) redm[wave] = m;
    __syncthreads();
    m = fmaxf(fmaxf(redm[0], redm[1]), fmaxf(redm[2], redm[3]));

    float s = 0.f;
#pragma unroll
    for (int j = 0; j < 8; j++) { v[j] = __expf(v[j] - m); s += v[j]; }
#pragma unroll
    for (int off = 32; off > 0; off >>= 1) s += __shfl_xor(s, off, 64);
    if (lane == 0) reds[wave] = s;
    __syncthreads();
    s = reds[0] + reds[1] + reds[2] + reds[3];

    const float inv = 1.0f / s;
#pragma unroll
    for (int j = 0; j < 8; j++) {
        const float p = v[j] * inv;
        rowp[j * 256 + tid] = p;
        rowb[j * 256 + tid] = f2bf(p);
    }
}

// ---------------------------------------------------------------------------
// context[b][m][n] = sum_l attn[m][l] * v[l][n] = NT GEMM(attn_bf, v^T)
// ---------------------------------------------------------------------------
__global__ __launch_bounds__(256) void context_kernel(
    const unsigned short* __restrict__ attn_bf, const unsigned short* __restrict__ vtb,
    float* __restrict__ ctx)
{
    __shared__ unsigned short sA[4096];
    __shared__ unsigned short sB[4096];
    const int bz = blockIdx.z;
    const unsigned short* Ag = attn_bf + (size_t)bz * L_ * L_;  // [2048][2048]
    const unsigned short* Bg = vtb + (size_t)bz * D_ * L_;      // [1024][2048]
    float* out = ctx + (size_t)bz * L_ * D_;

    const int m0 = blockIdx.x * 128;
    const int n0 = blockIdx.y * 128;
    GEMM_VARS

    f32x4 acc[4][4];
#pragma unroll
    for (int i = 0; i < 4; i++)
#pragma unroll
        for (int j = 0; j < 4; j++) acc[i][j] = (f32x4){0.f, 0.f, 0.f, 0.f};

    GEMM_KLOOP(Ag, L_, Bg, L_, L_)

#pragma unroll
    for (int i = 0; i < 4; i++) {
        const int m = m0 + wr * 64 + i * 16 + quad * 4;
#pragma unroll
        for (int j = 0; j < 4; j++) {
            const int n = n0 + wc * 64 + j * 16 + lrow;
#pragma unroll
            for (int r = 0; r < 4; r++)
                out[(size_t)(m + r) * D_ + n] = acc[i][j][r];
        }
    }
}

// ---------------------------------------------------------------------------
extern "C" void kernel_launch(void* const* d_in, const int* in_sizes, int n_in,
                              void* d_out, int out_size, void* d_ws, size_t ws_size,
                              hipStream_t stream) {
    const float* x    = (const float*)d_in[0];
    const int*   lens = (const int*)d_in[1];
    const float* y    = (const float*)d_in[2];
    const float* Wk   = (const float*)d_in[3];
    const float* Wv   = (const float*)d_in[4];
    const float* Wq   = (const float*)d_in[5];

    float* ctx  = (float*)d_out;                 // [B,L,D] fp32
    float* attn = (float*)d_out + CTX_ELEMS;     // [B,L,L] fp32

    // ws (proven-safe 100.7 MB): kb, qb, vtb.  attn_bf aliases kb+qb after scores.
    unsigned short* kb      = (unsigned short*)d_ws;
    unsigned short* qb      = kb + CTX_ELEMS;
    unsigned short* vtb     = qb + CTX_ELEMS;
    unsigned short* attn_bf = (unsigned short*)d_ws;

    // bf16 staging of inputs parked inside d_out's attn region (dead until scores)
    unsigned short* xb  = (unsigned short*)attn;
    unsigned short* yb  = xb + CTX_ELEMS;
    unsigned short* wkb = yb + CTX_ELEMS;
    unsigned short* wvb = wkb + D_ * D_;
    unsigned short* wqb = wvb + D_ * D_;

    cvt_kernel<<<dim3(2048, 5), 256, 0, stream>>>(x, y, Wk, Wv, Wq,
                                                  xb, yb, wkb, wvb, wqb);
    proj_kernel<<<dim3(128, 8, 3), 256, 0, stream>>>(xb, yb, wkb, wvb, wqb,
                                                     kb, qb, vtb);
    scores_kernel<<<dim3(16, 16, B_), 256, 0, stream>>>(qb, kb, attn);
    softmax_kernel<<<dim3(B_ * L_), 256, 0, stream>>>(attn, lens, attn_bf);
    context_kernel<<<dim3(16, 8, B_), 256, 0, stream>>>(attn_bf, vtb, ctx);
}

// Round 3
// 648.418 us; speedup vs baseline: 1.2012x; 1.0111x over previous
//
#include <hip/hip_runtime.h>
#include <hip/hip_bf16.h>

#define B_ 8
#define L_ 2048
#define D_ 1024
#define CTX_ELEMS (B_ * L_ * D_)   /* 16,777,216 */

typedef __bf16 bf16x8 __attribute__((ext_vector_type(8)));
typedef float f32x4 __attribute__((ext_vector_type(4)));
typedef unsigned short u16x8 __attribute__((ext_vector_type(8)));
typedef unsigned short u16x4 __attribute__((ext_vector_type(4)));

typedef __attribute__((address_space(1))) void GV;
typedef __attribute__((address_space(3))) void LV;
// async global->LDS, 16B per lane; LDS dst = wave-uniform base + lane*16
#define GLL16(g, l) __builtin_amdgcn_global_load_lds((GV*)(g), (LV*)(l), 16, 0, 0)

__device__ __forceinline__ unsigned short f2bf(float f) {
    union { float f; unsigned u; } c; c.f = f;
    unsigned u = c.u;
    u += 0x7fffu + ((u >> 16) & 1u);   // RNE
    return (unsigned short)(u >> 16);
}

// ---------------------------------------------------------------------------
// fp32 -> bf16 bulk convert.  blockIdx.y selects tensor.
// ---------------------------------------------------------------------------
__global__ __launch_bounds__(256) void cvt_kernel(
    const float* __restrict__ x, const float* __restrict__ y,
    const float* __restrict__ Wk, const float* __restrict__ Wv,
    const float* __restrict__ Wq,
    unsigned short* __restrict__ xb, unsigned short* __restrict__ yb,
    unsigned short* __restrict__ wkb, unsigned short* __restrict__ wvb,
    unsigned short* __restrict__ wqb)
{
    const float* src; unsigned short* dst; int n4;
    switch (blockIdx.y) {
        case 0:  src = x;  dst = xb;  n4 = CTX_ELEMS / 4; break;
        case 1:  src = y;  dst = yb;  n4 = CTX_ELEMS / 4; break;
        case 2:  src = Wk; dst = wkb; n4 = D_ * D_ / 4;   break;
        case 3:  src = Wv; dst = wvb; n4 = D_ * D_ / 4;   break;
        default: src = Wq; dst = wqb; n4 = D_ * D_ / 4;   break;
    }
    const int stride = gridDim.x * 256;
    for (int i = blockIdx.x * 256 + threadIdx.x; i < n4; i += stride) {
        float4 f = ((const float4*)src)[i];
        u16x4 o = { f2bf(f.x), f2bf(f.y), f2bf(f.z), f2bf(f.w) };
        ((u16x4*)dst)[i] = o;
    }
}

// ---------------------------------------------------------------------------
// m97-style NT GEMM core: out[m][n] = sum_k A[m][k]*B[n][k], 128x128x32 tiles.
// ---------------------------------------------------------------------------
#define GEMM_VARS                                              \
    const int tid = threadIdx.x;                               \
    const int wave = tid >> 6, lane = tid & 63;                \
    const int wr = wave >> 1, wc = wave & 1;                   \
    const int lrow = lane & 15, quad = lane >> 4;              \
    const int gr = lane >> 2, gc = (lane & 3) * 8;

#define GEMM_KLOOP(Ag, lda, Bg, ldb, K)                                        \
    for (int k0 = 0; k0 < (K); k0 += 32) {                                     \
        __syncthreads();                                                       \
        _Pragma("unroll")                                                      \
        for (int r = 0; r < 2; r++) {                                          \
            const int seg = wave * 2 + r;                                      \
            GLL16((Ag) + (size_t)(m0 + seg * 16 + gr) * (lda) + k0 + gc,       \
                  sA + seg * 512);                                             \
            GLL16((Bg) + (size_t)(n0 + seg * 16 + gr) * (ldb) + k0 + gc,       \
                  sB + seg * 512);                                             \
        }                                                                      \
        __syncthreads();                                                       \
        bf16x8 av[4], bv[4];                                                   \
        _Pragma("unroll")                                                      \
        for (int i = 0; i < 4; i++)                                            \
            av[i] = *(const bf16x8*)&sA[(wr * 64 + i * 16 + lrow) * 32 + quad * 8]; \
        _Pragma("unroll")                                                      \
        for (int j = 0; j < 4; j++)                                            \
            bv[j] = *(const bf16x8*)&sB[(wc * 64 + j * 16 + lrow) * 32 + quad * 8]; \
        _Pragma("unroll")                                                      \
        for (int i = 0; i < 4; i++)                                            \
            _Pragma("unroll")                                                  \
            for (int j = 0; j < 4; j++)                                        \
                acc[i][j] = __builtin_amdgcn_mfma_f32_16x16x32_bf16(           \
                    av[i], bv[j], acc[i][j], 0, 0, 0);                         \
    }

// ---------------------------------------------------------------------------
// Projections (all NT GEMMs, K=1024):
//   z=0: kb[l][d]  = x @ Wk^T   (A=x  M=16384, B=Wk N=1024)
//   z=1: vtb[d][l] = Wv @ x^T   (A=Wv M=1024,  B=x  N=16384)  -> v transposed
//   z=2: qb[l][d]  = y @ Wq^T   (A=y  M=16384, B=Wq N=1024)
// Epilogue restages through LDS so global bf16 stores are 256B-contiguous.
// ---------------------------------------------------------------------------
__global__ __launch_bounds__(256) void proj_kernel(
    const unsigned short* __restrict__ xb, const unsigned short* __restrict__ yb,
    const unsigned short* __restrict__ wkb, const unsigned short* __restrict__ wvb,
    const unsigned short* __restrict__ wqb,
    unsigned short* __restrict__ kb, unsigned short* __restrict__ qb,
    unsigned short* __restrict__ vtb)
{
    __shared__ unsigned short smem[8192];   // 16 KB: K-loop staging + epilogue restage
    unsigned short* sA = smem;
    unsigned short* sB = smem + 4096;

    const int z = blockIdx.z;
    // 4x4 super-tile swizzle over (bigdim=128 tiles, smalldim=8 tiles)
    const int lin = blockIdx.x;                 // 0..1023
    const int sq = lin >> 4, w = lin & 15;
    const int big = (sq & 31) * 4 + (w & 3);    // 0..127
    const int sml = (sq >> 5) * 4 + (w >> 2);   // 0..7
    int m0, n0;
    const unsigned short *Ag, *Bg;
    if (z == 0)      { Ag = xb;  Bg = wkb; m0 = big * 128; n0 = sml * 128; }
    else if (z == 1) { Ag = wvb; Bg = xb;  m0 = sml * 128; n0 = big * 128; }
    else             { Ag = yb;  Bg = wqb; m0 = big * 128; n0 = sml * 128; }

    GEMM_VARS

    f32x4 acc[4][4];
#pragma unroll
    for (int i = 0; i < 4; i++)
#pragma unroll
        for (int j = 0; j < 4; j++) acc[i][j] = (f32x4){0.f, 0.f, 0.f, 0.f};

    GEMM_KLOOP(Ag, D_, Bg, D_, D_)

    unsigned short* base; size_t ostride;
    if (z == 1) {
        base = vtb + (size_t)(n0 >> 11) * D_ * L_ + (size_t)m0 * L_ + (n0 & 2047);
        ostride = L_;
    } else {
        base = ((z == 0) ? kb : qb) + (size_t)m0 * D_ + n0;
        ostride = D_;
    }

    // epilogue: acc -> LDS (bf16) in two 64-row halves -> 256B coalesced stores
#pragma unroll
    for (int h = 0; h < 2; h++) {
        __syncthreads();
        if (wr == h) {
#pragma unroll
            for (int i = 0; i < 4; i++)
#pragma unroll
                for (int j = 0; j < 4; j++)
#pragma unroll
                    for (int r = 0; r < 4; r++)
                        smem[(i * 16 + quad * 4 + r) * 128 + wc * 64 + j * 16 + lrow]
                            = f2bf(acc[i][j][r]);
        }
        __syncthreads();
#pragma unroll
        for (int c = 0; c < 4; c++) {
            const int idx = c * 256 + tid;      // 0..1023
            const int rr  = idx >> 4;           // 0..63
            const int c8  = (idx & 15) * 8;
            *(u16x8*)(base + (size_t)(h * 64 + rr) * ostride + c8)
                = *(const u16x8*)&smem[rr * 128 + c8];
        }
    }
}

// ---------------------------------------------------------------------------
// scores[b][m][n] = (1/32) sum_d q[m][d] k[n][d]  -> fp32 attn
// ---------------------------------------------------------------------------
__global__ __launch_bounds__(256) void scores_kernel(
    const unsigned short* __restrict__ qb, const unsigned short* __restrict__ kb,
    float* __restrict__ attn)
{
    __shared__ unsigned short smem[8192];
    unsigned short* sA = smem;
    unsigned short* sB = smem + 4096;

    const int bz = blockIdx.z;
    const unsigned short* Ag = qb + (size_t)bz * L_ * D_;
    const unsigned short* Bg = kb + (size_t)bz * L_ * D_;
    float* out = attn + (size_t)bz * L_ * L_;

    // 4x4 super-tile swizzle over 16x16 tiles
    const int lin = blockIdx.x;                 // 0..255
    const int sq = lin >> 4, w = lin & 15;
    const int m0 = ((sq & 3) * 4 + (w & 3)) * 128;
    const int n0 = ((sq >> 2) * 4 + (w >> 2)) * 128;

    GEMM_VARS

    f32x4 acc[4][4];
#pragma unroll
    for (int i = 0; i < 4; i++)
#pragma unroll
        for (int j = 0; j < 4; j++) acc[i][j] = (f32x4){0.f, 0.f, 0.f, 0.f};

    GEMM_KLOOP(Ag, D_, Bg, D_, D_)

#pragma unroll
    for (int i = 0; i < 4; i++) {
        const int m = m0 + wr * 64 + i * 16 + quad * 4;
#pragma unroll
        for (int j = 0; j < 4; j++) {
            const int n = n0 + wc * 64 + j * 16 + lrow;
#pragma unroll
            for (int r = 0; r < 4; r++)
                out[(size_t)(m + r) * L_ + n] = acc[i][j][r] * 0.03125f;
        }
    }
}

// ---------------------------------------------------------------------------
// row softmax in place + bf16 copy.  Masked query rows -> exactly 1/2048.
// ---------------------------------------------------------------------------
__global__ __launch_bounds__(256) void softmax_kernel(
    float* __restrict__ attn, const int* __restrict__ lens,
    unsigned short* __restrict__ attn_bf)
{
    const int r  = blockIdx.x;
    const int b  = r >> 11;
    const int qi = r & 2047;
    float4* rowp = (float4*)(attn + (size_t)r * L_);
    u16x4*  rowb = (u16x4*)(attn_bf + (size_t)r * L_);
    const int tid = threadIdx.x;

    if (qi >= lens[b]) {
        const float u = 1.0f / 2048.0f;
        const unsigned short us = f2bf(u);
        const float4 uf = {u, u, u, u};
        const u16x4 ub = {us, us, us, us};
        rowp[tid] = uf; rowp[tid + 256] = uf;
        rowb[tid] = ub; rowb[tid + 256] = ub;
        return;
    }

    float4 v0 = rowp[tid], v1 = rowp[tid + 256];

    float m = fmaxf(fmaxf(fmaxf(v0.x, v0.y), fmaxf(v0.z, v0.w)),
                    fmaxf(fmaxf(v1.x, v1.y), fmaxf(v1.z, v1.w)));
#pragma unroll
    for (int off = 32; off > 0; off >>= 1) m = fmaxf(m, __shfl_xor(m, off, 64));

    __shared__ float redm[4];
    __shared__ float reds[4];
    const int wave = tid >> 6, lane = tid & 63;
    if (lane == 0) redm[wave] = m;
    __syncthreads();
    m = fmaxf(fmaxf(redm[0], redm[1]), fmaxf(redm[2], redm[3]));

    v0.x = __expf(v0.x - m); v0.y = __expf(v0.y - m);
    v0.z = __expf(v0.z - m); v0.w = __expf(v0.w - m);
    v1.x = __expf(v1.x - m); v1.y = __expf(v1.y - m);
    v1.z = __expf(v1.z - m); v1.w = __expf(v1.w - m);
    float s = (v0.x + v0.y) + (v0.z + v0.w) + (v1.x + v1.y) + (v1.z + v1.w);
#pragma unroll
    for (int off = 32; off > 0; off >>= 1) s += __shfl_xor(s, off, 64);
    if (lane == 0) reds[wave] = s;
    __syncthreads();
    s = reds[0] + reds[1] + reds[2] + reds[3];

    const float inv = 1.0f / s;
    v0.x *= inv; v0.y *= inv; v0.z *= inv; v0.w *= inv;
    v1.x *= inv; v1.y *= inv; v1.z *= inv; v1.w *= inv;
    rowp[tid] = v0; rowp[tid + 256] = v1;
    u16x4 b0 = { f2bf(v0.x), f2bf(v0.y), f2bf(v0.z), f2bf(v0.w) };
    u16x4 b1 = { f2bf(v1.x), f2bf(v1.y), f2bf(v1.z), f2bf(v1.w) };
    rowb[tid] = b0; rowb[tid + 256] = b1;
}

// ---------------------------------------------------------------------------
// context[b][m][n] = sum_l attn[m][l] * v[l][n] = NT GEMM(attn_bf, v^T)
// ---------------------------------------------------------------------------
__global__ __launch_bounds__(256) void context_kernel(
    const unsigned short* __restrict__ attn_bf, const unsigned short* __restrict__ vtb,
    float* __restrict__ ctx)
{
    __shared__ unsigned short smem[8192];
    unsigned short* sA = smem;
    unsigned short* sB = smem + 4096;

    const int bz = blockIdx.z;
    const unsigned short* Ag = attn_bf + (size_t)bz * L_ * L_;  // [2048][2048]
    const unsigned short* Bg = vtb + (size_t)bz * D_ * L_;      // [1024][2048]
    float* out = ctx + (size_t)bz * L_ * D_;

    // 4x4 super-tile swizzle over 16x8 tiles
    const int lin = blockIdx.x;                 // 0..127
    const int sq = lin >> 4, w = lin & 15;
    const int m0 = ((sq & 3) * 4 + (w & 3)) * 128;
    const int n0 = ((sq >> 2) * 4 + (w >> 2)) * 128;

    GEMM_VARS

    f32x4 acc[4][4];
#pragma unroll
    for (int i = 0; i < 4; i++)
#pragma unroll
        for (int j = 0; j < 4; j++) acc[i][j] = (f32x4){0.f, 0.f, 0.f, 0.f};

    GEMM_KLOOP(Ag, L_, Bg, L_, L_)

#pragma unroll
    for (int i = 0; i < 4; i++) {
        const int m = m0 + wr * 64 + i * 16 + quad * 4;
#pragma unroll
        for (int j = 0; j < 4; j++) {
            const int n = n0 + wc * 64 + j * 16 + lrow;
#pragma unroll
            for (int r = 0; r < 4; r++)
                out[(size_t)(m + r) * D_ + n] = acc[i][j][r];
        }
    }
}

// ---------------------------------------------------------------------------
extern "C" void kernel_launch(void* const* d_in, const int* in_sizes, int n_in,
                              void* d_out, int out_size, void* d_ws, size_t ws_size,
                              hipStream_t stream) {
    const float* x    = (const float*)d_in[0];
    const int*   lens = (const int*)d_in[1];
    const float* y    = (const float*)d_in[2];
    const float* Wk   = (const float*)d_in[3];
    const float* Wv   = (const float*)d_in[4];
    const float* Wq   = (const float*)d_in[5];

    float* ctx  = (float*)d_out;                 // [B,L,D] fp32
    float* attn = (float*)d_out + CTX_ELEMS;     // [B,L,L] fp32

    // ws: kb, qb, vtb (bf16).  attn_bf aliases kb+qb after scores (exactly spans both).
    unsigned short* kb      = (unsigned short*)d_ws;
    unsigned short* qb      = kb + CTX_ELEMS;
    unsigned short* vtb     = qb + CTX_ELEMS;
    unsigned short* attn_bf = (unsigned short*)d_ws;

    // bf16 staging of inputs parked inside d_out's attn region (dead until scores)
    unsigned short* xb  = (unsigned short*)attn;
    unsigned short* yb  = xb + CTX_ELEMS;
    unsigned short* wkb = yb + CTX_ELEMS;
    unsigned short* wvb = wkb + D_ * D_;
    unsigned short* wqb = wvb + D_ * D_;

    cvt_kernel<<<dim3(2048, 5), 256, 0, stream>>>(x, y, Wk, Wv, Wq,
                                                  xb, yb, wkb, wvb, wqb);
    proj_kernel<<<dim3(1024, 1, 3), 256, 0, stream>>>(xb, yb, wkb, wvb, wqb,
                                                      kb, qb, vtb);
    scores_kernel<<<dim3(256, 1, B_), 256, 0, stream>>>(qb, kb, attn);
    softmax_kernel<<<dim3(B_ * L_), 256, 0, stream>>>(attn, lens, attn_bf);
    context_kernel<<<dim3(128, 1, B_), 256, 0, stream>>>(attn_bf, vtb, ctx);
}